// Round 3
// baseline (120.491 us; speedup 1.0000x reference)
//
#include <hip/hip_runtime.h>
#include <math.h>

// FrequencyMaskingLoss — psychoacoustic masking loss (forward only, scalar out).
// Pipeline: [K0] init tables (f64 math) + control slots
//           [KA] STFT(ref & delta, one complex FFT) + PSDs + global max (atomicMax)
//           [KB] per-frame masking threshold + loss; last block reduces -> out[0]
// WINDOW=512, HOP=128, F=257, n_frames=(L-512)/128+1 (=1247 for L=160000).

#define FBINS 257

// table layout inside ws (floats)
#define TAB_BARK  0
#define TAB_ATHDB 257
#define TAB_ATHP  514
#define TAB_HANN  771
#define TAB_TWR   1283
#define TAB_TWI   1539
#define TAB_PSDMAX 1800   // uint, order-encoded float
#define TAB_COUNT  1801   // uint ticket counter
#define TAB_FLOATS 2048   // padded

// order-preserving float<->uint encoding (monotone: f1<f2 <=> enc(f1)<enc(f2))
__device__ inline unsigned enc_f(float f) {
    unsigned u = __float_as_uint(f);
    return (u & 0x80000000u) ? ~u : (u | 0x80000000u);
}
__device__ inline float dec_f(unsigned k) {
    return (k & 0x80000000u) ? __uint_as_float(k & 0x7fffffffu)
                             : __uint_as_float(~k);
}
__device__ inline float rl_f(float v, int l) {
    return __int_as_float(__builtin_amdgcn_readlane(__float_as_int(v), l));
}
__device__ inline int rl_i(int v, int l) {
    return __builtin_amdgcn_readlane(v, l);
}

// ---------------------------------------------------------------- kernel 0
__global__ __launch_bounds__(256) void k0_init(float* __restrict__ tab)
{
    const int tid = threadIdx.x;
    const double TWO_PI = 6.283185307179586476925286766559;
    for (int f = tid; f < FBINS; f += 256) {
        double freq = 31.25 * (double)f;            // SR/2/256 * f, exact
        double q    = freq / 7500.0;
        tab[TAB_BARK + f] = (float)(13.0 * atan(0.00076 * freq) + 3.5 * atan(q * q));
        if (f == 0) {
            tab[TAB_ATHDB] = -INFINITY;
            tab[TAB_ATHP]  = 0.0f;
        } else {
            double fk = freq * 0.001;
            double ad = 3.64 * pow(fk, -0.8)
                      - 6.5 * exp(-0.6 * (fk - 3.3) * (fk - 3.3))
                      + 0.001 * fk * fk * fk * fk - 12.0;
            float av = (float)ad;
            tab[TAB_ATHDB + f] = av;
            tab[TAB_ATHP  + f] = exp10f(av / 10.0f);
        }
    }
    for (int n = tid; n < 512; n += 256) {
        double cw = cos((TWO_PI * (double)n) / 512.0);
        tab[TAB_HANN + n] = (float)(0.5 * (1.0 - cw));
    }
    if (tid < 256) {
        double s, c;
        sincos(-(TWO_PI / 512.0) * (double)tid, &s, &c);
        tab[TAB_TWR + tid] = (float)c;
        tab[TAB_TWI + tid] = (float)s;
    }
    if (tid == 0) {
        ((unsigned*)tab)[TAB_PSDMAX] = 0u;   // < enc of any real value >= -200
        ((unsigned*)tab)[TAB_COUNT]  = 0u;
    }
}

// ---------------------------------------------------------------- kernel A
// One frame per block; z = hann*ref + i*hann*delta -> one 512-pt complex FFT.
// Ping-pong LDS: 1 barrier per stage. Global psd max via encoded atomicMax.
__global__ __launch_bounds__(256) void kA_stft(
    const float* __restrict__ xadv, const float* __restrict__ xref,
    const float* __restrict__ tab,
    float* __restrict__ psd_db, float* __restrict__ pd, unsigned* __restrict__ psdmax_u)
{
    __shared__ float reA[512], imA[512], reB[512], imB[512];
    __shared__ float twr[256], twi[256];
    __shared__ float wmax[4];
    const int t = blockIdx.x, tid = threadIdx.x;

    twr[tid] = tab[TAB_TWR + tid];
    twi[tid] = tab[TAB_TWI + tid];

    const int base_idx = t * 128;
    for (int n = tid; n < 512; n += 256) {
        float w = tab[TAB_HANN + n];
        float r = xref[base_idx + n];
        float a = xadv[base_idx + n];
        int   p = __brev((unsigned)n) >> 23;   // 9-bit reversal
        reA[p] = w * r;
        imA[p] = w * (a - r);
    }
    __syncthreads();

    // 9-stage radix-2 DIT, ping-pong buffers, one barrier per stage
    float *rs = reA, *is = imA, *rd = reB, *id = imB;
    for (int stage = 1; stage <= 9; ++stage) {
        int half  = 1 << (stage - 1);
        int tstep = 512 >> stage;
        int j     = tid & (half - 1);
        int base  = ((tid >> (stage - 1)) << stage) + j;
        float wr = twr[j * tstep], wi = twi[j * tstep];
        float vr0 = rs[base + half], vi0 = is[base + half];
        float vr = vr0 * wr - vi0 * wi;
        float vi = vr0 * wi + vi0 * wr;
        float ur = rs[base], ui = is[base];
        rd[base]        = ur + vr; id[base]        = ui + vi;
        rd[base + half] = ur - vr; id[base + half] = ui - vi;
        float* tp;
        tp = rs; rs = rd; rd = tp;
        tp = is; is = id; id = tp;
        __syncthreads();
    }

    // unpack A=rfft(ref), B=rfft(delta); PSDs
    const float S2 = 1.0172526041666667e-05f;   // (sqrt(8/3)/512)^2
    float lmax = -1e30f;
    {
        int k  = tid;                  // bins 0..255 by tid, bin 256 by tid 0 below
        int nk = (512 - k) & 511;
        float zr = rs[k],  zi = is[k];
        float yr = rs[nk], yi = is[nk];
        float ar = 0.5f * (zr + yr), ai = 0.5f * (zi - yi);   // ref spectrum
        float br = 0.5f * (zi + yi), bi = 0.5f * (yr - zr);   // delta spectrum
        float prefp = S2 * (ar * ar + ai * ai);
        float pdb   = fmaxf(10.0f * log10f(prefp), -200.0f);
        psd_db[t * FBINS + k] = pdb;
        pd[t * FBINS + k]     = S2 * (br * br + bi * bi);
        lmax = pdb;
        if (tid == 0) {                // bin 256 (Nyquist): z[256] real pair
            float zr2 = rs[256], zi2 = is[256];
            float prefp2 = S2 * (zr2 * zr2);
            float pdb2   = fmaxf(10.0f * log10f(prefp2), -200.0f);
            psd_db[t * FBINS + 256] = pdb2;
            pd[t * FBINS + 256]     = S2 * (zi2 * zi2);
            lmax = fmaxf(lmax, pdb2);
        }
    }
    for (int off = 32; off > 0; off >>= 1) lmax = fmaxf(lmax, __shfl_down(lmax, off));
    if ((tid & 63) == 0) wmax[tid >> 6] = lmax;
    __syncthreads();
    if (tid == 0) {
        float m = fmaxf(fmaxf(wmax[0], wmax[1]), fmaxf(wmax[2], wmax[3]));
        atomicMax(psdmax_u, enc_f(m));
    }
}

// ---------------------------------------------------------------- kernel B
__global__ __launch_bounds__(256) void kB_threshold(
    const float* __restrict__ tab,
    const float* __restrict__ psd_db, const float* __restrict__ pd,
    const unsigned* __restrict__ psdmax_u, unsigned* __restrict__ counter,
    float* __restrict__ floss, float* __restrict__ out, int nf)
{
    __shared__ float barkf[FBINS], athp_s[FBINS];
    __shared__ float p_s[FBINS], pw_s[FBINS];
    __shared__ float mc_s[128], shift_s[128], barkm_s[128], ups_s[128];
    __shared__ int   bin_s[128], keep_s[128], qmax_s[128];
    __shared__ int   wcnt[4];
    __shared__ float red[4];
    __shared__ int   amLast;

    const int t = blockIdx.x, tid = threadIdx.x;
    const int lane = tid & 63, wid = tid >> 6;
    const float pmax   = dec_f(psdmax_u[0]);
    const float shift0 = 96.0f - pmax;

    // tables + frame PSD into LDS
    for (int f = tid; f < FBINS; f += 256) {
        barkf[f]  = tab[TAB_BARK + f];
        athp_s[f] = tab[TAB_ATHP + f];
        float pv = shift0 + psd_db[t * FBINS + f];
        p_s[f]  = pv;
        pw_s[f] = exp10f(pv / 10.0f);
    }
    __syncthreads();

    // local-max + tonal masker level for f = tid
    float m = -1e30f;
    int   pred = 0;
    if (tid >= 1 && tid <= 255) {
        float pc = p_s[tid];
        if (pc > p_s[tid - 1] && pc > p_s[tid + 1]) {
            m = 10.0f * log10f((pw_s[tid] + pw_s[tid - 1]) + pw_s[tid + 1]);
            if (m > tab[TAB_ATHDB + tid]) pred = 1;
        }
    }
    // ballot stream-compaction (stable in frequency order)
    unsigned long long bal = __ballot(pred);
    if (lane == 0) wcnt[wid] = __popcll(bal);
    // qmax[p]: largest q>=p with (barkf[q]-barkf[p]) < 0.5f  (same fp expr as ref;
    // barkf monotone => first failure is the boundary). Position-indexed, data-free.
    if (tid < 128) {
        int q = tid;
        while (q + 1 < FBINS && (barkf[q + 1] - barkf[tid]) < 0.5f) ++q;
        qmax_s[tid] = q;
    }
    __syncthreads();
    int base = 0;
    for (int w = 0; w < wid; ++w) base += wcnt[w];
    const int n_total = wcnt[0] + wcnt[1] + wcnt[2] + wcnt[3];
    if (pred) {
        int pos = base + __popcll(bal & ((1ull << lane) - 1));
        bin_s[pos] = tid; mc_s[pos] = m; keep_s[pos] = 1;
    }
    __syncthreads();

    // lane-resident copies for the serial scan: wave 0, lane l holds pos l and l+64
    float mcw0 = 0.0f, mcw1 = 0.0f;
    int   qmw0 = 0,    qmw1 = 0;
    if (wid == 0) {
        mcw0 = mc_s[lane];        mcw1 = mc_s[lane + 64];
        qmw0 = qmax_s[lane];      qmw1 = qmax_s[lane + 64];
    }
    // sequential i_prev scan (faithful, incl. position-indexed BARK[]):
    // thread 0 only; all reads via v_readlane (no LDS latency chain)
    if (tid == 0 && n_total > 1) {
        int   i_prev = 0;
        float mcp = rl_f(mcw0, 0);
        int   qmp = rl_i(qmw0, 0);
        for (int i = 1; i < n_total; ++i) {
            float mci = (i < 64) ? rl_f(mcw0, i) : rl_f(mcw1, i - 64);
            bool close = (i <= qmp);                 // == (barkf[i]-barkf[i_prev] < 0.5f)
            bool ps    = mcp < mci;
            if (close) {
                keep_s[ps ? i_prev : i] = 0;
                if (ps) {
                    i_prev += 1;
                    mcp = (i_prev < 64) ? rl_f(mcw0, i_prev) : rl_f(mcw1, i_prev - 64);
                    qmp = (i_prev < 64) ? rl_i(qmw0, i_prev) : rl_i(qmw1, i_prev - 64);
                }
            } else {
                i_prev = i;
                mcp = mci;
                qmp = (i < 64) ? rl_i(qmw0, i) : rl_i(qmw1, i - 64);
            }
        }
    }
    __syncthreads();

    // compact kept maskers, precompute per-masker terms
    int pred2 = (tid < n_total) && keep_s[tid];
    unsigned long long bal2 = __ballot(pred2);
    if (lane == 0) wcnt[wid] = __popcll(bal2);
    __syncthreads();
    int base2 = 0;
    for (int w = 0; w < wid; ++w) base2 += wcnt[w];
    const int nk = wcnt[0] + wcnt[1] + wcnt[2] + wcnt[3];
    if (pred2) {
        int pos = base2 + __popcll(bal2 & ((1ull << lane) - 1));
        int   fb = bin_s[tid];
        float mc = mc_s[tid];
        shift_s[pos] = mc + (-6.025f - 0.275f * barkf[fb]);
        barkm_s[pos] = barkf[fb];
        ups_s[pos]   = -27.0f + 0.37f * fmaxf(mc - 40.0f, 0.0f);
    }
    __syncthreads();

    // per-bin threshold power + loss (threshold kept in POWER domain)
    const float C = 3981071705.534973f / exp10f(pmax / 10.0f);  // 10^9.6/10^(pmax/10)
    float lsum = 0.0f;
    for (int f = tid; f < FBINS; f += 256) {
        float bf  = barkf[f];
        float acc = 0.0f;
        for (int k = 0; k < nk; ++k) {
            float dz    = bf - barkm_s[k];
            float slope = (dz > 0.0f) ? ups_s[k] : 27.0f;
            float tdb   = shift_s[k] + slope * dz;
            acc += exp10f(tdb / 10.0f);
        }
        float thrpow = acc + athp_s[f];
        float pds    = C * pd[t * FBINS + f];
        lsum += fmaxf(pds - thrpow, 0.0f);
    }
    for (int off = 32; off > 0; off >>= 1) lsum += __shfl_down(lsum, off);
    if ((tid & 63) == 0) red[tid >> 6] = lsum;
    __syncthreads();
    if (tid == 0) {
        floss[t] = (red[0] + red[1]) + (red[2] + red[3]);
        __threadfence();
        unsigned old = atomicAdd(counter, 1u);
        amLast = (old == (unsigned)(gridDim.x - 1));
    }
    __syncthreads();

    // last block: deterministic final mean
    if (amLast) {
        __threadfence();
        float s = 0.0f;
        for (int i = tid; i < nf; i += 256) s += floss[i];
        for (int off = 32; off > 0; off >>= 1) s += __shfl_down(s, off);
        if ((tid & 63) == 0) red[tid >> 6] = s;
        __syncthreads();
        if (tid == 0) {
            float total = (red[0] + red[1]) + (red[2] + red[3]);
            out[0] = 1e-6f * (total / (float)(nf * FBINS));
        }
    }
}

// ---------------------------------------------------------------- launch
extern "C" void kernel_launch(void* const* d_in, const int* in_sizes, int n_in,
                              void* d_out, int out_size, void* d_ws, size_t ws_size,
                              hipStream_t stream)
{
    const float* x_adv = (const float*)d_in[0];
    const float* x_ref = (const float*)d_in[1];
    float*       out   = (float*)d_out;

    const int L  = in_sizes[0];
    const int nf = (L - 512) / 128 + 1;           // 1247 for L=160000

    float* ws      = (float*)d_ws;
    float* tab     = ws;                                   // TAB_FLOATS
    float* psd_db  = ws + TAB_FLOATS;                      // nf*257
    float* pd      = psd_db + (size_t)nf * FBINS;          // nf*257
    float* floss   = pd + (size_t)nf * FBINS;              // nf
    unsigned* psdmax_u = (unsigned*)tab + TAB_PSDMAX;
    unsigned* counter  = (unsigned*)tab + TAB_COUNT;

    k0_init     <<<1,  256, 0, stream>>>(tab);
    kA_stft     <<<nf, 256, 0, stream>>>(x_adv, x_ref, tab, psd_db, pd, psdmax_u);
    kB_threshold<<<nf, 256, 0, stream>>>(tab, psd_db, pd, psdmax_u, counter,
                                         floss, out, nf);
}

// Round 4
// 115.680 us; speedup vs baseline: 1.0416x; 1.0416x over previous
//
#include <hip/hip_runtime.h>
#include <math.h>

// FrequencyMaskingLoss — psychoacoustic masking loss (forward only, scalar out).
// R4: one WAVE per frame (4 frames / 256-thread block), wave-synchronous LDS
// (no s_barrier in hot paths). [K0] tables  [KA] STFT+PSD+global max
// [KB] per-frame threshold + loss, last block reduces.
// WINDOW=512, HOP=128, F=257, n_frames=(L-512)/128+1 (=1247 for L=160000).

#define FBINS 257
#define FPB   4     // frames per block = waves per block

// table layout inside ws (floats)
#define TAB_BARK   0
#define TAB_ATHDB  257
#define TAB_ATHP   514
#define TAB_HANN   771
#define TAB_TWR    1283
#define TAB_TWI    1539
#define TAB_PSDMAX 1800   // uint, order-encoded float
#define TAB_COUNT  1801   // uint ticket counter
#define TAB_FLOATS 2048

// order-preserving float<->uint encoding
__device__ inline unsigned enc_f(float f) {
    unsigned u = __float_as_uint(f);
    return (u & 0x80000000u) ? ~u : (u | 0x80000000u);
}
__device__ inline float dec_f(unsigned k) {
    return (k & 0x80000000u) ? __uint_as_float(k & 0x7fffffffu)
                             : __uint_as_float(~k);
}
__device__ inline float rl_f(float v, int l) {
    return __int_as_float(__builtin_amdgcn_readlane(__float_as_int(v), l));
}
__device__ inline int rl_i(int v, int l) {
    return __builtin_amdgcn_readlane(v, l);
}
// wave-level LDS sync: DS ops of a wave complete in order; drain + compiler fence
__device__ __forceinline__ void wave_lds_sync() {
    asm volatile("s_waitcnt lgkmcnt(0)" ::: "memory");
}

// ---------------------------------------------------------------- kernel 0
__global__ __launch_bounds__(256) void k0_init(float* __restrict__ tab)
{
    const int tid = threadIdx.x;
    const double TWO_PI = 6.283185307179586476925286766559;
    for (int f = tid; f < FBINS; f += 256) {
        double freq = 31.25 * (double)f;
        double q    = freq / 7500.0;
        tab[TAB_BARK + f] = (float)(13.0 * atan(0.00076 * freq) + 3.5 * atan(q * q));
        if (f == 0) {
            tab[TAB_ATHDB] = -INFINITY;
            tab[TAB_ATHP]  = 0.0f;
        } else {
            double fk = freq * 0.001;
            double ad = 3.64 * pow(fk, -0.8)
                      - 6.5 * exp(-0.6 * (fk - 3.3) * (fk - 3.3))
                      + 0.001 * fk * fk * fk * fk - 12.0;
            float av = (float)ad;
            tab[TAB_ATHDB + f] = av;
            tab[TAB_ATHP  + f] = exp10f(av / 10.0f);
        }
    }
    for (int n = tid; n < 512; n += 256) {
        double cw = cos((TWO_PI * (double)n) / 512.0);
        tab[TAB_HANN + n] = (float)(0.5 * (1.0 - cw));
    }
    if (tid < 256) {
        double s, c;
        sincos(-(TWO_PI / 512.0) * (double)tid, &s, &c);
        tab[TAB_TWR + tid] = (float)c;
        tab[TAB_TWI + tid] = (float)s;
    }
    if (tid == 0) {
        ((unsigned*)tab)[TAB_PSDMAX] = 0u;
        ((unsigned*)tab)[TAB_COUNT]  = 0u;
    }
}

// ---------------------------------------------------------------- kernel A
// 4 frames/block, one per wave. Cooperative staging (1 barrier), then each
// wave does an in-place 512-pt FFT in its LDS slice, wave-synchronously.
__global__ __launch_bounds__(256) void kA_stft(
    const float* __restrict__ xadv, const float* __restrict__ xref,
    const float* __restrict__ tab, int L, int nf,
    float* __restrict__ psd_db, float* __restrict__ pd,
    unsigned* __restrict__ psdmax_u)
{
    __shared__ float xs[896], dss[896];          // FPB*128 + 512 - 128 = 896
    __shared__ float hann[512], twr[256], twi[256];
    __shared__ float fre[FPB][512], fim[FPB][512];

    const int tid = threadIdx.x, lane = tid & 63, w = tid >> 6;
    const int g0 = blockIdx.x * (FPB * 128);

    for (int i = tid; i < 896; i += 256) {
        int g = g0 + i;
        float r = (g < L) ? xref[g] : 0.0f;
        float a = (g < L) ? xadv[g] : 0.0f;
        xs[i] = r; dss[i] = a - r;
    }
    for (int n = tid; n < 512; n += 256) hann[n] = tab[TAB_HANN + n];
    twr[tid] = tab[TAB_TWR + tid];
    twi[tid] = tab[TAB_TWI + tid];
    __syncthreads();                              // the only block barrier

    const int t = blockIdx.x * FPB + w;
    if (t < nf) {
        float* rs  = fre[w];
        float* is_ = fim[w];
        // windowed load + bit-reverse scatter (z = hann*ref + i*hann*delta)
        for (int n = lane; n < 512; n += 64) {
            float wn = hann[n];
            int   p  = __brev((unsigned)n) >> 23;
            rs[p]  = wn * xs[w * 128 + n];
            is_[p] = wn * dss[w * 128 + n];
        }
        wave_lds_sync();
        // 9-stage radix-2 DIT, in-place, 4 butterflies/lane/stage
        for (int stage = 1; stage <= 9; ++stage) {
            int half = 1 << (stage - 1), tstep = 512 >> stage;
            #pragma unroll
            for (int it = 0; it < 4; ++it) {
                int b    = lane + 64 * it;
                int j    = b & (half - 1);
                int base = ((b >> (stage - 1)) << stage) + j;
                float wr = twr[j * tstep], wi = twi[j * tstep];
                float vr0 = rs[base + half], vi0 = is_[base + half];
                float vr = vr0 * wr - vi0 * wi;
                float vi = vr0 * wi + vi0 * wr;
                float ur = rs[base], ui = is_[base];
                rs[base]         = ur + vr; is_[base]         = ui + vi;
                rs[base + half]  = ur - vr; is_[base + half]  = ui - vi;
            }
            wave_lds_sync();
        }
        // unpack A=rfft(ref), B=rfft(delta); PSDs; per-frame max
        const float S2 = 1.0172526041666667e-05f;   // (sqrt(8/3)/512)^2
        float lmax = -1e30f;
        for (int j2 = 0; j2 < 5; ++j2) {
            int k = lane + 64 * j2;
            if (k <= 256) {
                int nk2 = (512 - k) & 511;
                float zr = rs[k],   zi = is_[k];
                float yr = rs[nk2], yi = is_[nk2];
                float ar = 0.5f * (zr + yr), ai = 0.5f * (zi - yi);
                float br = 0.5f * (zi + yi), bi = 0.5f * (yr - zr);
                float prefp = S2 * (ar * ar + ai * ai);
                float pdb   = fmaxf(10.0f * log10f(prefp), -200.0f);
                psd_db[(size_t)t * FBINS + k] = pdb;
                pd[(size_t)t * FBINS + k]     = S2 * (br * br + bi * bi);
                lmax = fmaxf(lmax, pdb);
            }
        }
        for (int off = 32; off > 0; off >>= 1)
            lmax = fmaxf(lmax, __shfl_down(lmax, off));
        if (lane == 0) atomicMax(psdmax_u, enc_f(lmax));
    }
}

// ---------------------------------------------------------------- kernel B
__global__ __launch_bounds__(256) void kB_threshold(
    const float* __restrict__ tab,
    const float* __restrict__ psd_db, const float* __restrict__ pd,
    const unsigned* __restrict__ psdmax_u, unsigned* __restrict__ counter,
    float* __restrict__ floss, float* __restrict__ out, int nf)
{
    __shared__ float barkf[FBINS], athdb_s[FBINS], athp_s[FBINS];
    __shared__ float p_s[FPB][FBINS + 3], pw_s[FPB][FBINS + 3];
    __shared__ float mc_s[FPB][128];
    __shared__ int   bin_s[FPB][128];
    __shared__ float shift_s[FPB][128], barkm_s[FPB][128], ups_s[FPB][128];
    __shared__ float red[4];
    __shared__ int   amLast;

    const int tid = threadIdx.x, lane = tid & 63, w = tid >> 6;
    const float pmax   = dec_f(psdmax_u[0]);
    const float shift0 = 96.0f - pmax;

    for (int f = tid; f < FBINS; f += 256) {
        barkf[f]   = tab[TAB_BARK + f];
        athdb_s[f] = tab[TAB_ATHDB + f];
        athp_s[f]  = tab[TAB_ATHP + f];
    }
    __syncthreads();                              // tables ready

    const int t = blockIdx.x * FPB + w;
    if (t < nf) {
        // qmax for positions lane and lane+64: largest q with bark diff < 0.5
        // (position-indexed per the reference's faithful replication; barkf
        //  monotone => i<=qmax[p]  <=>  (barkf[i]-barkf[p]) < 0.5f)
        int qm0, qm1;
        {
            float b0 = barkf[lane];
            int q = lane;
            while (q + 1 < FBINS && (barkf[q + 1] - b0) < 0.5f) ++q;
            qm0 = q;
            float b1 = barkf[lane + 64];
            q = lane + 64;
            while (q + 1 < FBINS && (barkf[q + 1] - b1) < 0.5f) ++q;
            qm1 = q;
        }
        // frame PSD -> p (dB), pw (power)
        const float* prow = psd_db + (size_t)t * FBINS;
        for (int j = 0; j < 5; ++j) {
            int f = lane + 64 * j;
            if (f < FBINS) {
                float pv = shift0 + prow[f];
                p_s[w][f]  = pv;
                pw_s[w][f] = exp10f(pv / 10.0f);
            }
        }
        wave_lds_sync();
        // candidate maskers: local max above ATH; ballot compaction, j-major
        float mreg[4]; int predj[4], cnt[4];
        unsigned long long balj[4];
        #pragma unroll
        for (int j = 0; j < 4; ++j) {
            int f = lane + 64 * j;
            int pred = 0; float m = -1e30f;
            if (f >= 1 && f <= 255) {
                float pc = p_s[w][f];
                if (pc > p_s[w][f - 1] && pc > p_s[w][f + 1]) {
                    m = 10.0f * log10f((pw_s[w][f] + pw_s[w][f - 1]) + pw_s[w][f + 1]);
                    if (m > athdb_s[f]) pred = 1;
                }
            }
            mreg[j] = m; predj[j] = pred;
            balj[j] = __ballot(pred);
            cnt[j]  = __popcll(balj[j]);
        }
        const int n_total = cnt[0] + cnt[1] + cnt[2] + cnt[3];
        int basej = 0;
        #pragma unroll
        for (int j = 0; j < 4; ++j) {
            if (predj[j]) {
                int pos = basej + __popcll(balj[j] & ((1ull << lane) - 1));
                mc_s[w][pos]  = mreg[j];
                bin_s[w][pos] = lane + 64 * j;
            }
            basej += cnt[j];
        }
        wave_lds_sync();
        // lane-resident masker levels: lane l holds positions l and l+64
        float mcw0 = mc_s[w][lane], mcw1 = mc_s[w][lane + 64];
        // sequential i_prev scan (faithful): lane 0, keep-flags in registers
        unsigned long long keep0 = ~0ull, keep1 = ~0ull;
        if (lane == 0 && n_total > 1) {
            int   i_prev = 0;
            float mcp = rl_f(mcw0, 0);
            int   qmp = rl_i(qm0, 0);
            for (int i = 1; i < n_total; ++i) {
                float mci = (i < 64) ? rl_f(mcw0, i) : rl_f(mcw1, i - 64);
                bool close = (i <= qmp);
                bool ps    = mcp < mci;
                if (close) {
                    int del = ps ? i_prev : i;
                    if (del < 64) keep0 &= ~(1ull << del);
                    else          keep1 &= ~(1ull << (del - 64));
                    if (ps) {
                        i_prev += 1;
                        mcp = (i_prev < 64) ? rl_f(mcw0, i_prev) : rl_f(mcw1, i_prev - 64);
                        qmp = (i_prev < 64) ? rl_i(qm0, i_prev)  : rl_i(qm1, i_prev - 64);
                    }
                } else {
                    i_prev = i;
                    mcp = mci;
                    qmp = (i < 64) ? rl_i(qm0, i) : rl_i(qm1, i - 64);
                }
            }
        }
        keep0 = __shfl(keep0, 0);
        keep1 = __shfl(keep1, 0);
        // recompact kept maskers directly from the masks
        unsigned long long v0 = (n_total >= 64) ? ~0ull
                              : ((n_total > 0) ? ((1ull << n_total) - 1) : 0ull);
        int rem = n_total - 64;
        unsigned long long v1 = (rem >= 64) ? ~0ull
                              : ((rem > 0) ? ((1ull << rem) - 1) : 0ull);
        unsigned long long k0m = keep0 & v0, k1m = keep1 & v1;
        const int nk  = __popcll(k0m) + __popcll(k1m);
        const int nk0 = __popcll(k0m);
        if (k0m & (1ull << lane)) {
            int pos = __popcll(k0m & ((1ull << lane) - 1));
            int fb  = bin_s[w][lane];
            float mc = mcw0;
            shift_s[w][pos] = mc + (-6.025f - 0.275f * barkf[fb]);
            barkm_s[w][pos] = barkf[fb];
            ups_s[w][pos]   = -27.0f + 0.37f * fmaxf(mc - 40.0f, 0.0f);
        }
        if (k1m & (1ull << lane)) {
            int pos = nk0 + __popcll(k1m & ((1ull << lane) - 1));
            int fb  = bin_s[w][lane + 64];
            float mc = mcw1;
            shift_s[w][pos] = mc + (-6.025f - 0.275f * barkf[fb]);
            barkm_s[w][pos] = barkf[fb];
            ups_s[w][pos]   = -27.0f + 0.37f * fmaxf(mc - 40.0f, 0.0f);
        }
        wave_lds_sync();
        // per-bin threshold power + loss (POWER domain: skip log/exp round-trip)
        const float C = 3981071705.534973f / exp10f(pmax / 10.0f); // 10^9.6/10^(pmax/10)
        const float* pdrow = pd + (size_t)t * FBINS;
        float lsum = 0.0f;
        for (int j = 0; j < 5; ++j) {
            int f = lane + 64 * j;
            if (f < FBINS) {
                float bf  = barkf[f];
                float acc = 0.0f;
                for (int k = 0; k < nk; ++k) {
                    float dz    = bf - barkm_s[w][k];
                    float slope = (dz > 0.0f) ? ups_s[w][k] : 27.0f;
                    float tdb   = shift_s[w][k] + slope * dz;
                    acc += exp10f(tdb / 10.0f);
                }
                float thrpow = acc + athp_s[f];
                lsum += fmaxf(C * pdrow[f] - thrpow, 0.0f);
            }
        }
        for (int off = 32; off > 0; off >>= 1) lsum += __shfl_down(lsum, off);
        if (lane == 0) floss[t] = lsum;
    }
    __syncthreads();
    if (tid == 0) {
        __threadfence();
        unsigned old = atomicAdd(counter, 1u);
        amLast = (old == (unsigned)(gridDim.x - 1));
    }
    __syncthreads();
    if (amLast) {
        __threadfence();
        float s = 0.0f;
        for (int i = tid; i < nf; i += 256) s += floss[i];
        for (int off = 32; off > 0; off >>= 1) s += __shfl_down(s, off);
        if ((tid & 63) == 0) red[tid >> 6] = s;
        __syncthreads();
        if (tid == 0) {
            float total = (red[0] + red[1]) + (red[2] + red[3]);
            out[0] = 1e-6f * (total / (float)(nf * FBINS));
        }
    }
}

// ---------------------------------------------------------------- launch
extern "C" void kernel_launch(void* const* d_in, const int* in_sizes, int n_in,
                              void* d_out, int out_size, void* d_ws, size_t ws_size,
                              hipStream_t stream)
{
    const float* x_adv = (const float*)d_in[0];
    const float* x_ref = (const float*)d_in[1];
    float*       out   = (float*)d_out;

    const int L  = in_sizes[0];
    const int nf = (L - 512) / 128 + 1;           // 1247 for L=160000
    const int nb = (nf + FPB - 1) / FPB;          // 312

    float* ws      = (float*)d_ws;
    float* tab     = ws;                                   // TAB_FLOATS
    float* psd_db  = ws + TAB_FLOATS;                      // nf*257
    float* pd      = psd_db + (size_t)nf * FBINS;          // nf*257
    float* floss   = pd + (size_t)nf * FBINS;              // nf
    unsigned* psdmax_u = (unsigned*)tab + TAB_PSDMAX;
    unsigned* counter  = (unsigned*)tab + TAB_COUNT;

    k0_init     <<<1,  256, 0, stream>>>(tab);
    kA_stft     <<<nb, 256, 0, stream>>>(x_adv, x_ref, tab, L, nf,
                                         psd_db, pd, psdmax_u);
    kB_threshold<<<nb, 256, 0, stream>>>(tab, psd_db, pd, psdmax_u, counter,
                                         floss, out, nf);
}